// Round 9
// baseline (119.048 us; speedup 1.0000x reference)
//
#include <hip/hip_runtime.h>
#include <hip/hip_bf16.h>

// UVCrossAttention — MI355X (gfx950), Round 12: R9 monolith + bf16-prep.
//
// R11 post-mortem: doubling waves/CU again returned ~0 (mono ~40 vs R9 ~36)
// -> split-phase is BYTE-throughput bound at the CU memory port, not
// latency-bound. Lever: halve the bytes. New tiny prep dispatch converts
//   W_off, W_attn -> plain bf16            (streaming phase: half bytes)
//   value, W_v    -> bf16 PRE-SWIZZLED     (byte = r*256 + ((cc*16)^((r&15)<<4)))
// so mono's MFMA staging is a pure linear 16B copy (source pre-swizzled +
// swizzled read = same involution both sides), no pack VALU, half bytes.
// Mono structure is byte-identical R9 (best measured: ~36 µs) otherwise.
// 2 dispatches: prep(168x256) -> mono(256x512). Workspace < 1 MB.

#define NQ   1024
#define NV   1024
#define ND   128
#define NP   4
#define IMG_W 32
#define IMG_H 32
#define QB   4

// workspace byte offsets
#define WS_VAL   0         // value  bf16 swizzled, 1024*128*2 = 256 KB
#define WS_WV    262144    // W_v    bf16 swizzled, 32 KB
#define WS_WOFF  294912    // W_off  bf16 plain [128][1024], 256 KB
#define WS_WATTN 557056    // W_attn bf16 plain [128][512], 128 KB

typedef __attribute__((ext_vector_type(8))) short bfx8;
typedef __attribute__((ext_vector_type(4))) float f32x4;

__device__ __forceinline__ unsigned short bf_rne(float f) {
  union { __hip_bfloat16 h; unsigned short u; } v;
  v.h = __float2bfloat16(f);
  return v.u;
}
__device__ __forceinline__ float bf2f(unsigned short u) {
  return __uint_as_float((unsigned)u << 16);
}
__device__ __forceinline__ bfx8 pack8(const float* p) {
  bfx8 v;
#pragma unroll
  for (int j = 0; j < 8; ++j) v[j] = (short)bf_rne(p[j]);
  return v;
}

// ---------------------------------------------------------------------------
// prep: fp32 -> bf16 conversions (value/W_v into MFMA-swizzled layout).
// 43008 chunks of 8 floats; grid 168 x 256.
// ---------------------------------------------------------------------------
__global__ __launch_bounds__(256) void prep_kernel(
    const float* __restrict__ value, const float* __restrict__ W_v,
    const float* __restrict__ W_off, const float* __restrict__ W_attn,
    char* __restrict__ ws) {
  const int idx = blockIdx.x * 256 + threadIdx.x;
  if (idx < 16384) {                       // value: row 0..1023, cc 0..15
    const int row = idx >> 4, cc = idx & 15;
    const bfx8 v = pack8(value + (size_t)row * 128 + cc * 8);
    *(bfx8*)(ws + WS_VAL + row * 256 + ((cc * 16) ^ ((row & 15) << 4))) = v;
  } else if (idx < 18432) {                // W_v: row 0..127, cc 0..15
    const int j = idx - 16384;
    const int row = j >> 4, cc = j & 15;
    const bfx8 v = pack8(W_v + (size_t)row * 128 + cc * 8);
    *(bfx8*)(ws + WS_WV + row * 256 + ((cc * 16) ^ ((row & 15) << 4))) = v;
  } else if (idx < 34816) {                // W_off plain: 16384 chunks
    const int j = idx - 18432;
    const bfx8 v = pack8(W_off + (size_t)j * 8);
    *(bfx8*)(ws + WS_WOFF + (size_t)j * 16) = v;
  } else if (idx < 43008) {                // W_attn plain: 8192 chunks
    const int j = idx - 34816;
    const bfx8 v = pack8(W_attn + (size_t)j * 8);
    *(bfx8*)(ws + WS_WATTN + (size_t)j * 16) = v;
  }
}

// ---------------------------------------------------------------------------
__global__ __launch_bounds__(512) void mono_kernel(
    const float* __restrict__ query, const float* __restrict__ key,
    const float* __restrict__ ref3d,
    const float* __restrict__ b_off, const float* __restrict__ b_attn,
    const float* __restrict__ b_v,
    const float* __restrict__ W_o, const float* __restrict__ b_o,
    const char* __restrict__ ws, float* __restrict__ out) {
  __shared__ float q_lds[QB][128];                    // 2 KB
  __shared__ float key_lds[QB][128];                  // 2 KB
  __shared__ float keyp_lds[QB][128];                 // 2 KB
  __shared__ float c_lds[QB];
  __shared__ unsigned short img_bf[QB][NV];           // 8 KB
  __shared__ unsigned short off_bf[QB][1024];         // 8 KB
  __shared__ unsigned short aw_bf[QB][512];           // 4 KB
  __shared__ __align__(16) unsigned short sval[128 * 128];  // 32 KB
  float* o1s = (float*)sval;                          // phase 4/5 overlay

  const int tid = threadIdx.x;
  const int q0 = blockIdx.x * QB;
  const int w = tid >> 6, l = tid & 63;
  const int col = l & 15, g = l >> 4;

  const char* wsval = ws + WS_VAL;
  const char* wswv = ws + WS_WV;
  const unsigned short* wswoff = (const unsigned short*)(ws + WS_WOFF);
  const unsigned short* wswattn = (const unsigned short*)(ws + WS_WATTN);

  // ---- 1. stage q & key rows; copy W_v (pre-swizzled bf16) into sval
  if (tid < 128) {
    ((float4*)q_lds)[tid] = ((const float4*)(query + (size_t)q0 * 128))[tid];
  } else if (tid < 256) {
    ((float4*)key_lds)[tid - 128] =
        ((const float4*)(key + (size_t)q0 * 128))[tid - 128];
  }
#pragma unroll
  for (int it = 0; it < 4; ++it) {
    const int c = tid + it * 512;          // 2048 chunks of 16 B
    *(bfx8*)((char*)sval + c * 16) = *(const bfx8*)(wswv + (size_t)c * 16);
  }
  __syncthreads();

  // ---- 2. keyp = key @ W_v^T (all 8 waves; wave w -> embed rows w*16..+15)
  {
    bfx8 afK[4];
#pragma unroll
    for (int ks = 0; ks < 4; ++ks) {
      bfx8 a;
      if (col < QB) {
        a = pack8(&key_lds[col][ks * 32 + g * 8]);
      } else {
#pragma unroll
        for (int j = 0; j < 8; ++j) a[j] = 0;
      }
      afK[ks] = a;
    }
    {
      const int r = w * 16 + col;          // W_v row = keyp embed index
      f32x4 acc = {0.f, 0.f, 0.f, 0.f};
#pragma unroll
      for (int ks = 0; ks < 4; ++ks) {
        const int colb = (ks * 64 + g * 16) ^ (col << 4);
        const bfx8 bfr = *(const bfx8*)((const char*)sval + r * 256 + colb);
        acc = __builtin_amdgcn_mfma_f32_16x16x32_bf16(afK[ks], bfr, acc,
                                                      0, 0, 0);
      }
      if (g == 0) {
#pragma unroll
        for (int i = 0; i < QB; ++i) keyp_lds[i][r] = acc[i];
      }
    }
    if (tid < QB) {   // c[qq] = key[qq]·b_v (b_v == 0 here; kept for generality)
      float s = 0.f;
      for (int e = 0; e < 128; e += 4) {
        const float4 bv = *(const float4*)(b_v + e);
        const float4 k4 = *(const float4*)(&key_lds[tid][e]);
        s = fmaf(bv.x, k4.x,
            fmaf(bv.y, k4.y, fmaf(bv.z, k4.z, fmaf(bv.w, k4.w, s))));
      }
      c_lds[tid] = s;
    }
  }
  __syncthreads();

  // ---- 3. SPLIT: waves 0-3 -> off/aw streaming (bf16 weights);
  //               waves 4-7 -> img MFMA (pre-swizzled value copy)
  if (w < 4) {
    // thread t (0..255) owns off cols 4t..4t+3, aw cols 2t..2t+1
    const int t = tid;
    float4 aoff[QB];
    float2 aaw[QB];
#pragma unroll
    for (int qq = 0; qq < QB; ++qq) {
      aoff[qq] = make_float4(0.f, 0.f, 0.f, 0.f);
      aaw[qq] = make_float2(0.f, 0.f);
    }
    const unsigned short* wo_p = wswoff + t * 4;
    const unsigned short* wa_p = wswattn + t * 2;
#pragma unroll 4
    for (int e4 = 0; e4 < 32; ++e4) {
      float4 q4[QB];
#pragma unroll
      for (int qq = 0; qq < QB; ++qq)
        q4[qq] = *(const float4*)(&q_lds[qq][e4 * 4]);
#pragma unroll
      for (int j = 0; j < 4; ++j) {
        const int e = e4 * 4 + j;
        const uint2 uw = *(const uint2*)(wo_p + (size_t)e * 1024);
        const unsigned ua = *(const unsigned*)(wa_p + (size_t)e * 512);
        const float w0 = bf2f((unsigned short)(uw.x & 0xffff));
        const float w1 = bf2f((unsigned short)(uw.x >> 16));
        const float w2 = bf2f((unsigned short)(uw.y & 0xffff));
        const float w3 = bf2f((unsigned short)(uw.y >> 16));
        const float wa0 = bf2f((unsigned short)(ua & 0xffff));
        const float wa1 = bf2f((unsigned short)(ua >> 16));
#pragma unroll
        for (int qq = 0; qq < QB; ++qq) {
          const float qv = ((const float*)&q4[qq])[j];  // static (j unrolled)
          aoff[qq].x = fmaf(qv, w0, aoff[qq].x);
          aoff[qq].y = fmaf(qv, w1, aoff[qq].y);
          aoff[qq].z = fmaf(qv, w2, aoff[qq].z);
          aoff[qq].w = fmaf(qv, w3, aoff[qq].w);
          aaw[qq].x = fmaf(qv, wa0, aaw[qq].x);
          aaw[qq].y = fmaf(qv, wa1, aaw[qq].y);
        }
      }
    }
    const float4 bo4 = *(const float4*)(b_off + t * 4);
    const float2 ba2 = *(const float2*)(b_attn + t * 2);
#pragma unroll
    for (int qq = 0; qq < QB; ++qq) {
      const unsigned lo = (unsigned)bf_rne(aoff[qq].x + bo4.x) |
                          ((unsigned)bf_rne(aoff[qq].y + bo4.y) << 16);
      const unsigned hi = (unsigned)bf_rne(aoff[qq].z + bo4.z) |
                          ((unsigned)bf_rne(aoff[qq].w + bo4.w) << 16);
      *(uint2*)(&off_bf[qq][t * 4]) = make_uint2(lo, hi);
      *(unsigned*)(&aw_bf[qq][t * 2]) =
          (unsigned)bf_rne(aaw[qq].x + ba2.x) |
          ((unsigned)bf_rne(aaw[qq].y + ba2.y) << 16);
    }
  } else {
    // wave ww owns v rows ww*256..+255; 8 subtiles of 32 rows, wave-local
    // 8 KB buffer. Staging = pure linear 16B copy (source pre-swizzled).
    const int ww = w - 4;
    unsigned short* buf = sval + ww * 4096;
    bfx8 afrag[4];
#pragma unroll
    for (int ks = 0; ks < 4; ++ks) {
      bfx8 a;
      if (col < QB) {
        a = pack8(&keyp_lds[col][ks * 32 + g * 8]);
      } else {
#pragma unroll
        for (int j = 0; j < 8; ++j) a[j] = 0;
      }
      afrag[ks] = a;
    }
    float cq[QB];
#pragma unroll
    for (int i = 0; i < QB; ++i) cq[i] = c_lds[i];

    for (int sub = 0; sub < 8; ++sub) {
      const int vbase = ww * 256 + sub * 32;
      const char* src = wsval + (size_t)vbase * 256;  // 8 KB subtile
#pragma unroll
      for (int it = 0; it < 8; ++it) {
        const int c = l + it * 64;           // 512 chunks of 16 B
        *(bfx8*)((char*)buf + c * 16) = *(const bfx8*)(src + (size_t)c * 16);
      }
      // (same-wave ds_write->ds_read: compiler inserts lgkmcnt waits)
#pragma unroll
      for (int cg = 0; cg < 2; ++cg) {
        const int r = cg * 16 + col;         // row within 32-row subtile
        f32x4 acc = {0.f, 0.f, 0.f, 0.f};
#pragma unroll
        for (int ks = 0; ks < 4; ++ks) {
          const int colb = (ks * 64 + g * 16) ^ (col << 4);
          const bfx8 bfr = *(const bfx8*)((const char*)buf + r * 256 + colb);
          acc = __builtin_amdgcn_mfma_f32_16x16x32_bf16(afrag[ks], bfr, acc,
                                                        0, 0, 0);
        }
        if (g == 0) {
          const int v = vbase + r;
#pragma unroll
          for (int i = 0; i < QB; ++i)
            img_bf[i][v] = bf_rne(acc[i] + cq[i]);
        }
      }
    }
  }
  __syncthreads();

  // ---- 4. sampling: (qq,d) = (tid>>7, tid&127)
  {
    const int qq = tid >> 7;
    const int q = q0 + qq;
    const int d = tid & 127;
    const unsigned short* im = img_bf[qq];
    const size_t qe = (size_t)q * ND + d;

    const float rx = ref3d[qe * 2 + 0];
    const float ry = ref3d[qe * 2 + 1];

    const uint2 ua = *(const uint2*)(&aw_bf[qq][d * 4]);
    const float a0 = bf2f((unsigned short)(ua.x & 0xffff));
    const float a1 = bf2f((unsigned short)(ua.x >> 16));
    const float a2 = bf2f((unsigned short)(ua.y & 0xffff));
    const float a3 = bf2f((unsigned short)(ua.y >> 16));
    const float mx = fmaxf(fmaxf(a0, a1), fmaxf(a2, a3));
    const float e0 = __expf(a0 - mx), e1 = __expf(a1 - mx),
                e2 = __expf(a2 - mx), e3 = __expf(a3 - mx);
    const float inv = 1.0f / (e0 + e1 + e2 + e3);
    const float wgt4[4] = {e0 * inv, e1 * inv, e2 * inv, e3 * inv};

    const uint4 uo = *(const uint4*)(&off_bf[qq][d * 8]);
    const unsigned ox[4] = {uo.x, uo.y, uo.z, uo.w};

    float acc = 0.0f;
#pragma unroll
    for (int p = 0; p < NP; ++p) {
      const float x = rx * (float)IMG_W + bf2f((unsigned short)(ox[p] & 0xffff)) - 0.5f;
      const float y = ry * (float)IMG_H + bf2f((unsigned short)(ox[p] >> 16)) - 0.5f;
      const float xf = floorf(x), yf = floorf(y);
      const int ix0 = (int)xf, iy0 = (int)yf;
      const float wx1 = x - xf, wy1 = y - yf;
      const float wx0 = 1.0f - wx1, wy0 = 1.0f - wy1;

      float s = 0.0f;
#pragma unroll
      for (int cy = 0; cy < 2; ++cy) {
#pragma unroll
        for (int cx = 0; cx < 2; ++cx) {
          const int ix = ix0 + cx, iy = iy0 + cy;
          const bool valid = (ix >= 0) & (ix < IMG_W) & (iy >= 0) & (iy < IMG_H);
          const int cix = min(max(ix, 0), IMG_W - 1);
          const int ciy = min(max(iy, 0), IMG_H - 1);
          const float wgt = (cx ? wx1 : wx0) * (cy ? wy1 : wy0);
          s += valid ? bf2f(im[ciy * IMG_W + cix]) * wgt : 0.0f;
        }
      }
      acc += wgt4[p] * s;
    }
    o1s[qq * ND + d] = acc * (1.0f / 128.0f);  // overlays dead sval
  }
  __syncthreads();

  // ---- 5. out[q][n] = o1s[q]·W_o[:,n] + b_o[n] + query[q][n]
  {
    const int qq = tid >> 7;
    const int n = tid & 127;
    float acc = b_o[n] + q_lds[qq][n];
#pragma unroll 8
    for (int d = 0; d < 128; ++d)
      acc = fmaf(o1s[qq * ND + d], W_o[(size_t)d * 128 + n], acc);
    out[(size_t)(q0 + qq) * 128 + n] = acc;
  }
}

// ---------------------------------------------------------------------------
extern "C" void kernel_launch(void* const* d_in, const int* in_sizes, int n_in,
                              void* d_out, int out_size, void* d_ws, size_t ws_size,
                              hipStream_t stream) {
  const float* query  = (const float*)d_in[0];
  const float* key    = (const float*)d_in[1];
  const float* value  = (const float*)d_in[2];
  const float* ref3d  = (const float*)d_in[3];
  // d_in[4] = spatial_shapes [[32,32]] (hardcoded)
  const float* W_off  = (const float*)d_in[5];
  const float* b_off  = (const float*)d_in[6];
  const float* W_attn = (const float*)d_in[7];
  const float* b_attn = (const float*)d_in[8];
  const float* W_v    = (const float*)d_in[9];
  const float* b_v    = (const float*)d_in[10];
  const float* W_o    = (const float*)d_in[11];
  const float* b_o    = (const float*)d_in[12];
  float* out = (float*)d_out;
  char* ws = (char*)d_ws;

  prep_kernel<<<168, 256, 0, stream>>>(value, W_v, W_off, W_attn, ws);
  mono_kernel<<<NQ / QB, 512, 0, stream>>>(query, key, ref3d,
                                           b_off, b_attn, b_v, W_o, b_o,
                                           ws, out);
}

// Round 10
// 101.203 us; speedup vs baseline: 1.1763x; 1.1763x over previous
//
#include <hip/hip_runtime.h>
#include <hip/hip_bf16.h>

// UVCrossAttention — MI355X (gfx950), Round 13: R9 base + explicit 2-deep
// register pipelines (T14 async-stage) in both wave-specialized halves.
//
// Evidence so far: bytes/2 (R12) -> slower; waves x2 (R11) -> ~0; direct
// global at VGPR-48 (R10) -> slower. OccupancyPercent ~20% at BOTH 8 and 16
// resident waves => ~6.5 waves unstalled; waves sit in s_waitcnt on serial
// load->consume chains. Fix = overlap, not more waves / fewer bytes:
//   * streaming half: W_off/W_attn fp32 in 32 blocks of 4 rows, named A/B
//     register buffers, SLOAD(k+1) interleaved with SFMA(k).
//   * value half: prep pre-swizzles value/W_v to bf16; lanes load MFMA
//     B-fragments DIRECTLY at swizzled addresses (wave = bijection over a
//     contiguous 4KB region, 16B granules), 2-subtile-deep pipeline.
//     No LDS staging, no pack VALU, no barriers in the loop.
// Named live buffers force VGPR allocation (defeats the VGPR-collapse
// failure mode). LDS 28 KB. 2 dispatches: prep(72x256) -> mono(256x512).

#define NQ   1024
#define NV   1024
#define ND   128
#define NP   4
#define IMG_W 32
#define IMG_H 32
#define QB   4

#define WS_VAL 0         // value bf16 swizzled: 1024 rows x 256 B = 256 KB
#define WS_WV  262144    // W_v   bf16 swizzled: 128 rows x 256 B = 32 KB

typedef __attribute__((ext_vector_type(8))) short bfx8;
typedef __attribute__((ext_vector_type(4))) float f32x4;

__device__ __forceinline__ unsigned short bf_rne(float f) {
  union { __hip_bfloat16 h; unsigned short u; } v;
  v.h = __float2bfloat16(f);
  return v.u;
}
__device__ __forceinline__ float bf2f(unsigned short u) {
  return __uint_as_float((unsigned)u << 16);
}
__device__ __forceinline__ bfx8 pack8(const float* p) {
  bfx8 v;
#pragma unroll
  for (int j = 0; j < 8; ++j) v[j] = (short)bf_rne(p[j]);
  return v;
}

// ---------------------------------------------------------------------------
// prep: value + W_v -> bf16 in the MFMA-swizzled layout
//   byte(row, cc) = row*256 + ((cc*16) ^ ((row&15)<<4))
// ---------------------------------------------------------------------------
__global__ __launch_bounds__(256) void prep_kernel(
    const float* __restrict__ value, const float* __restrict__ W_v,
    char* __restrict__ ws) {
  const int idx = blockIdx.x * 256 + threadIdx.x;
  if (idx < 16384) {                       // value: row 0..1023, cc 0..15
    const int row = idx >> 4, cc = idx & 15;
    const bfx8 v = pack8(value + (size_t)row * 128 + cc * 8);
    *(bfx8*)(ws + WS_VAL + row * 256 + ((cc * 16) ^ ((row & 15) << 4))) = v;
  } else if (idx < 18432) {                // W_v: row 0..127, cc 0..15
    const int j = idx - 16384;
    const int row = j >> 4, cc = j & 15;
    const bfx8 v = pack8(W_v + (size_t)row * 128 + cc * 8);
    *(bfx8*)(ws + WS_WV + row * 256 + ((cc * 16) ^ ((row & 15) << 4))) = v;
  }
}

// streaming-half pipeline macros (blocks of 4 e-rows)
#define SLOAD(WO, WA, bb)                                                \
  _Pragma("unroll") for (int j_ = 0; j_ < 4; ++j_) {                     \
    WO[j_] = *(const float4*)(wo_p + (size_t)((bb) * 4 + j_) * 1024);    \
    WA[j_] = *(const float2*)(wa_p + (size_t)((bb) * 4 + j_) * 512);     \
  }

#define SFMA(WO, WA, bb)                                                 \
  _Pragma("unroll") for (int j_ = 0; j_ < 4; ++j_) {                     \
    const int e_ = (bb) * 4 + j_;                                        \
    _Pragma("unroll") for (int qq_ = 0; qq_ < QB; ++qq_) {               \
      const float qv_ = q_lds[qq_][e_];                                  \
      aoff[qq_].x = fmaf(qv_, WO[j_].x, aoff[qq_].x);                    \
      aoff[qq_].y = fmaf(qv_, WO[j_].y, aoff[qq_].y);                    \
      aoff[qq_].z = fmaf(qv_, WO[j_].z, aoff[qq_].z);                    \
      aoff[qq_].w = fmaf(qv_, WO[j_].w, aoff[qq_].w);                    \
      aaw[qq_].x = fmaf(qv_, WA[j_].x, aaw[qq_].x);                      \
      aaw[qq_].y = fmaf(qv_, WA[j_].y, aaw[qq_].y);                      \
    }                                                                    \
  }

// value-half pipeline macros (subtiles of 32 v-rows; 8 bfx8 frags each)
#define VLOAD(D, s_)                                                     \
  {                                                                      \
    const char* p_ = lanep + (size_t)(s_) * 8192;                        \
    D[0] = *(const bfx8*)(p_ + cb0);                                     \
    D[1] = *(const bfx8*)(p_ + cb1);                                     \
    D[2] = *(const bfx8*)(p_ + cb2);                                     \
    D[3] = *(const bfx8*)(p_ + cb3);                                     \
    D[4] = *(const bfx8*)(p_ + 4096 + cb0);                              \
    D[5] = *(const bfx8*)(p_ + 4096 + cb1);                              \
    D[6] = *(const bfx8*)(p_ + 4096 + cb2);                              \
    D[7] = *(const bfx8*)(p_ + 4096 + cb3);                              \
  }

#define VCOMP(S, s_)                                                     \
  {                                                                      \
    f32x4 a0_ = {0.f, 0.f, 0.f, 0.f}, a1_ = {0.f, 0.f, 0.f, 0.f};       \
    a0_ = __builtin_amdgcn_mfma_f32_16x16x32_bf16(afrag[0], S[0], a0_, 0, 0, 0); \
    a0_ = __builtin_amdgcn_mfma_f32_16x16x32_bf16(afrag[1], S[1], a0_, 0, 0, 0); \
    a0_ = __builtin_amdgcn_mfma_f32_16x16x32_bf16(afrag[2], S[2], a0_, 0, 0, 0); \
    a0_ = __builtin_amdgcn_mfma_f32_16x16x32_bf16(afrag[3], S[3], a0_, 0, 0, 0); \
    a1_ = __builtin_amdgcn_mfma_f32_16x16x32_bf16(afrag[0], S[4], a1_, 0, 0, 0); \
    a1_ = __builtin_amdgcn_mfma_f32_16x16x32_bf16(afrag[1], S[5], a1_, 0, 0, 0); \
    a1_ = __builtin_amdgcn_mfma_f32_16x16x32_bf16(afrag[2], S[6], a1_, 0, 0, 0); \
    a1_ = __builtin_amdgcn_mfma_f32_16x16x32_bf16(afrag[3], S[7], a1_, 0, 0, 0); \
    if (g == 0) {                                                        \
      const int v_ = ww * 256 + (s_) * 32 + col;                         \
      _Pragma("unroll") for (int i_ = 0; i_ < QB; ++i_) {                \
        img_bf[i_][v_] = bf_rne(a0_[i_] + cq[i_]);                       \
        img_bf[i_][v_ + 16] = bf_rne(a1_[i_] + cq[i_]);                  \
      }                                                                  \
    }                                                                    \
  }

// ---------------------------------------------------------------------------
__global__ __launch_bounds__(512, 2) void mono_kernel(
    const float* __restrict__ query, const float* __restrict__ key,
    const float* __restrict__ ref3d,
    const float* __restrict__ W_off, const float* __restrict__ b_off,
    const float* __restrict__ W_attn, const float* __restrict__ b_attn,
    const float* __restrict__ b_v,
    const float* __restrict__ W_o, const float* __restrict__ b_o,
    const char* __restrict__ ws, float* __restrict__ out) {
  __shared__ float q_lds[QB][128];                    // 2 KB
  __shared__ float key_lds[QB][128];                  // 2 KB
  __shared__ float keyp_lds[QB][128];                 // 2 KB
  __shared__ float c_lds[QB];
  __shared__ unsigned short img_bf[QB][NV];           // 8 KB
  __shared__ unsigned short off_bf[QB][1024];         // 8 KB
  __shared__ unsigned short aw_bf[QB][512];           // 4 KB
  __shared__ float o1s[QB][128];                      // 2 KB  (~28 KB total)

  const int tid = threadIdx.x;
  const int q0 = blockIdx.x * QB;
  const int w = tid >> 6, l = tid & 63;
  const int col = l & 15, g = l >> 4;

  // swizzled chunk offsets for this lane (shared by keyp + value paths)
  const int cb0 = (0 + g * 16) ^ (col << 4);
  const int cb1 = (64 + g * 16) ^ (col << 4);
  const int cb2 = (128 + g * 16) ^ (col << 4);
  const int cb3 = (192 + g * 16) ^ (col << 4);

  const char* wsval = ws + WS_VAL;
  const char* wswv = ws + WS_WV;

  // ---- 1. stage q & key rows (coalesced float4)
  if (tid < 128) {
    ((float4*)q_lds)[tid] = ((const float4*)(query + (size_t)q0 * 128))[tid];
  } else if (tid < 256) {
    ((float4*)key_lds)[tid - 128] =
        ((const float4*)(key + (size_t)q0 * 128))[tid - 128];
  }
  __syncthreads();

  // ---- 2. keyp = key @ W_v^T (all 8 waves; W_v fragments direct-global)
  {
    bfx8 afK[4];
#pragma unroll
    for (int ks = 0; ks < 4; ++ks) {
      bfx8 a;
      if (col < QB) {
        a = pack8(&key_lds[col][ks * 32 + g * 8]);
      } else {
#pragma unroll
        for (int j = 0; j < 8; ++j) a[j] = 0;
      }
      afK[ks] = a;
    }
    {
      const char* kvp = wswv + (size_t)(w * 16 + col) * 256;
      const bfx8 b0 = *(const bfx8*)(kvp + cb0);
      const bfx8 b1 = *(const bfx8*)(kvp + cb1);
      const bfx8 b2 = *(const bfx8*)(kvp + cb2);
      const bfx8 b3 = *(const bfx8*)(kvp + cb3);
      f32x4 acc = {0.f, 0.f, 0.f, 0.f};
      acc = __builtin_amdgcn_mfma_f32_16x16x32_bf16(afK[0], b0, acc, 0, 0, 0);
      acc = __builtin_amdgcn_mfma_f32_16x16x32_bf16(afK[1], b1, acc, 0, 0, 0);
      acc = __builtin_amdgcn_mfma_f32_16x16x32_bf16(afK[2], b2, acc, 0, 0, 0);
      acc = __builtin_amdgcn_mfma_f32_16x16x32_bf16(afK[3], b3, acc, 0, 0, 0);
      if (g == 0) {
#pragma unroll
        for (int i = 0; i < QB; ++i) keyp_lds[i][w * 16 + col] = acc[i];
      }
    }
    if (tid < QB) {   // c[qq] = key[qq]·b_v (b_v == 0 here; kept for generality)
      float s = 0.f;
      for (int e = 0; e < 128; e += 4) {
        const float4 bv = *(const float4*)(b_v + e);
        const float4 k4 = *(const float4*)(&key_lds[tid][e]);
        s = fmaf(bv.x, k4.x,
            fmaf(bv.y, k4.y, fmaf(bv.z, k4.z, fmaf(bv.w, k4.w, s))));
      }
      c_lds[tid] = s;
    }
  }
  __syncthreads();

  // ---- 3. SPLIT: waves 0-3 -> off/aw (fp32, 2-deep reg pipeline);
  //               waves 4-7 -> img MFMA (direct swizzled bf16, 2-deep)
  if (w < 4) {
    const int t = tid;   // 0..255: off cols 4t..4t+3, aw cols 2t..2t+1
    float4 aoff[QB];
    float2 aaw[QB];
#pragma unroll
    for (int qq = 0; qq < QB; ++qq) {
      aoff[qq] = make_float4(0.f, 0.f, 0.f, 0.f);
      aaw[qq] = make_float2(0.f, 0.f);
    }
    const float* wo_p = W_off + (size_t)t * 4;
    const float* wa_p = W_attn + (size_t)t * 2;

    float4 woA[4], woB[4];
    float2 waA[4], waB[4];
    SLOAD(woA, waA, 0);
    for (int b = 0; b < 32; b += 2) {
      SLOAD(woB, waB, b + 1);        // prefetch odd block
      SFMA(woA, waA, b);             // consume even block
      if (b + 2 < 32) SLOAD(woA, waA, b + 2);  // prefetch next even
      SFMA(woB, waB, b + 1);         // consume odd block
    }

    const float4 bo4 = *(const float4*)(b_off + t * 4);
    const float2 ba2 = *(const float2*)(b_attn + t * 2);
#pragma unroll
    for (int qq = 0; qq < QB; ++qq) {
      const unsigned lo = (unsigned)bf_rne(aoff[qq].x + bo4.x) |
                          ((unsigned)bf_rne(aoff[qq].y + bo4.y) << 16);
      const unsigned hi = (unsigned)bf_rne(aoff[qq].z + bo4.z) |
                          ((unsigned)bf_rne(aoff[qq].w + bo4.w) << 16);
      *(uint2*)(&off_bf[qq][t * 4]) = make_uint2(lo, hi);
      *(unsigned*)(&aw_bf[qq][t * 2]) =
          (unsigned)bf_rne(aaw[qq].x + ba2.x) |
          ((unsigned)bf_rne(aaw[qq].y + ba2.y) << 16);
    }
  } else {
    // wave ww owns v rows ww*256..+255 (8 subtiles of 32 rows)
    const int ww = w - 4;
    bfx8 afrag[4];
#pragma unroll
    for (int ks = 0; ks < 4; ++ks) {
      bfx8 a;
      if (col < QB) {
        a = pack8(&keyp_lds[col][ks * 32 + g * 8]);
      } else {
#pragma unroll
        for (int j = 0; j < 8; ++j) a[j] = 0;
      }
      afrag[ks] = a;
    }
    float cq[QB];
#pragma unroll
    for (int i = 0; i < QB; ++i) cq[i] = c_lds[i];

    const char* lanep = wsval + ((size_t)ww * 256 + col) * 256;
    bfx8 vA[8], vB[8];
    VLOAD(vA, 0);
    for (int s = 0; s < 8; s += 2) {
      VLOAD(vB, s + 1);              // prefetch odd subtile
      VCOMP(vA, s);                  // consume even subtile
      if (s + 2 < 8) VLOAD(vA, s + 2);
      VCOMP(vB, s + 1);
    }
  }
  __syncthreads();

  // ---- 4. sampling: (qq,d) = (tid>>7, tid&127)
  {
    const int qq = tid >> 7;
    const int q = q0 + qq;
    const int d = tid & 127;
    const unsigned short* im = img_bf[qq];
    const size_t qe = (size_t)q * ND + d;

    const float rx = ref3d[qe * 2 + 0];
    const float ry = ref3d[qe * 2 + 1];

    const uint2 ua = *(const uint2*)(&aw_bf[qq][d * 4]);
    const float a0 = bf2f((unsigned short)(ua.x & 0xffff));
    const float a1 = bf2f((unsigned short)(ua.x >> 16));
    const float a2 = bf2f((unsigned short)(ua.y & 0xffff));
    const float a3 = bf2f((unsigned short)(ua.y >> 16));
    const float mx = fmaxf(fmaxf(a0, a1), fmaxf(a2, a3));
    const float e0 = __expf(a0 - mx), e1 = __expf(a1 - mx),
                e2 = __expf(a2 - mx), e3 = __expf(a3 - mx);
    const float inv = 1.0f / (e0 + e1 + e2 + e3);
    const float wgt4[4] = {e0 * inv, e1 * inv, e2 * inv, e3 * inv};

    const uint4 uo = *(const uint4*)(&off_bf[qq][d * 8]);
    const unsigned ox[4] = {uo.x, uo.y, uo.z, uo.w};

    float acc = 0.0f;
#pragma unroll
    for (int p = 0; p < NP; ++p) {
      const float x = rx * (float)IMG_W + bf2f((unsigned short)(ox[p] & 0xffff)) - 0.5f;
      const float y = ry * (float)IMG_H + bf2f((unsigned short)(ox[p] >> 16)) - 0.5f;
      const float xf = floorf(x), yf = floorf(y);
      const int ix0 = (int)xf, iy0 = (int)yf;
      const float wx1 = x - xf, wy1 = y - yf;
      const float wx0 = 1.0f - wx1, wy0 = 1.0f - wy1;

      float s = 0.0f;
#pragma unroll
      for (int cy = 0; cy < 2; ++cy) {
#pragma unroll
        for (int cx = 0; cx < 2; ++cx) {
          const int ix = ix0 + cx, iy = iy0 + cy;
          const bool valid = (ix >= 0) & (ix < IMG_W) & (iy >= 0) & (iy < IMG_H);
          const int cix = min(max(ix, 0), IMG_W - 1);
          const int ciy = min(max(iy, 0), IMG_H - 1);
          const float wgt = (cx ? wx1 : wx0) * (cy ? wy1 : wy0);
          s += valid ? bf2f(im[ciy * IMG_W + cix]) * wgt : 0.0f;
        }
      }
      acc += wgt4[p] * s;
    }
    o1s[qq][d] = acc * (1.0f / 128.0f);
  }
  __syncthreads();

  // ---- 5. out[q][n] = o1s[q]·W_o[:,n] + b_o[n] + query[q][n]
  {
    const int qq = tid >> 7;
    const int n = tid & 127;
    float acc = b_o[n] + q_lds[qq][n];
#pragma unroll 8
    for (int d = 0; d < 128; ++d)
      acc = fmaf(o1s[qq][d], W_o[(size_t)d * 128 + n], acc);
    out[(size_t)(q0 + qq) * 128 + n] = acc;
  }
}

// ---------------------------------------------------------------------------
extern "C" void kernel_launch(void* const* d_in, const int* in_sizes, int n_in,
                              void* d_out, int out_size, void* d_ws, size_t ws_size,
                              hipStream_t stream) {
  const float* query  = (const float*)d_in[0];
  const float* key    = (const float*)d_in[1];
  const float* value  = (const float*)d_in[2];
  const float* ref3d  = (const float*)d_in[3];
  // d_in[4] = spatial_shapes [[32,32]] (hardcoded)
  const float* W_off  = (const float*)d_in[5];
  const float* b_off  = (const float*)d_in[6];
  const float* W_attn = (const float*)d_in[7];
  const float* b_attn = (const float*)d_in[8];
  const float* W_v    = (const float*)d_in[9];
  const float* b_v    = (const float*)d_in[10];
  const float* W_o    = (const float*)d_in[11];
  const float* b_o    = (const float*)d_in[12];
  float* out = (float*)d_out;
  char* ws = (char*)d_ws;

  prep_kernel<<<72, 256, 0, stream>>>(value, W_v, ws);
  mono_kernel<<<NQ / QB, 512, 0, stream>>>(query, key, ref3d,
                                           W_off, b_off, W_attn, b_attn,
                                           b_v, W_o, b_o, ws, out);
}